// Round 1
// baseline (174.193 us; speedup 1.0000x reference)
//
#include <hip/hip_runtime.h>
#include <hip/hip_bf16.h>

#define NPAIRS 500000
#define NNODES 100000
#define DIM    128
#define D2     256
#define BM     128
#define NBLK   ((NPAIRS + BM - 1) / BM)   // 3907

typedef __bf16 bf16;
typedef __bf16 bf16x8 __attribute__((ext_vector_type(8)));
typedef float  f32x4  __attribute__((ext_vector_type(4)));

// Pack W1 (256x256 fp32, row k = input-dim, col n = output-dim) into bf16
// MFMA B-fragments laid out in exact per-lane load order:
// w1f[((cg*8 + kk)*64 + lane)*8 + j] = W1[kk*32 + (lane>>4)*8 + j][cg*16 + (lane&15)]
__global__ void pack_w1(const float* __restrict__ W1, bf16* __restrict__ w1f) {
    int t = blockIdx.x * 256 + threadIdx.x;   // 0..8191
    int lane = t & 63;
    int kkcg = t >> 6;                        // cg*8 + kk
    int kk = kkcg & 7;
    int cg = kkcg >> 3;
    int l15 = lane & 15, lg = lane >> 4;
    bf16x8 v;
#pragma unroll
    for (int j = 0; j < 8; ++j) {
        int k = kk * 32 + lg * 8 + j;
        int n = cg * 16 + l15;
        v[j] = (bf16)W1[k * D2 + n];
    }
    *(bf16x8*)((char*)w1f + ((long)t << 4)) = v;
}

__launch_bounds__(256, 2)
__global__ void gnn_main(const float* __restrict__ x,
                         const int*   __restrict__ junc,
                         const bf16*  __restrict__ w1f,
                         const float* __restrict__ b1,
                         const float* __restrict__ w2p,
                         const float* __restrict__ b2,
                         float*       __restrict__ out) {
    __shared__ char  atile[BM * 512];   // 64 KB: [128 rows][256 bf16], XOR-swizzled
    __shared__ float outp[4][BM];       // per-wave partial row sums

    int tid = threadIdx.x;
    long base_p = (long)blockIdx.x * BM;

    // ---- stage: gather x rows, convert fp32->bf16, write swizzled LDS tile ----
    // 4096 tasks of 8 elements (16B LDS write / 32B global read), 16 iters x 256 thr.
    // 16 consecutive threads cover one 512B node-row -> fully coalesced.
#pragma unroll
    for (int it = 0; it < 16; ++it) {
        int task  = it * 256 + tid;     // 0..4095
        int nr    = task >> 4;          // node-row 0..255
        int chunk = task & 15;          // 8-element chunk within the 128-float row
        int r     = nr >> 1;            // pair row within block
        int side  = nr & 1;
        long p    = base_p + r;
        int idx   = (p < NPAIRS) ? junc[p * 2 + side] : 0;
        const float4* src = (const float4*)(x + (long)idx * DIM + chunk * 8);
        float4 a = src[0];
        float4 b = src[1];
        bf16x8 v;
        v[0] = (bf16)a.x; v[1] = (bf16)a.y; v[2] = (bf16)a.z; v[3] = (bf16)a.w;
        v[4] = (bf16)b.x; v[5] = (bf16)b.y; v[6] = (bf16)b.z; v[7] = (bf16)b.w;
        int byte_in_row = side * 256 + chunk * 16;
        int boff = r * 512 + (byte_in_row ^ ((r & 7) << 4));
        *(bf16x8*)(atile + boff) = v;
    }
    __syncthreads();

    // ---- MFMA: H = A(128x256) @ W1(256x256), wave owns cols [wave*64, +64) ----
    int wave = tid >> 6;
    int lane = tid & 63;
    int l15 = lane & 15, lg = lane >> 4;

    f32x4 acc[8][4];
#pragma unroll
    for (int m = 0; m < 8; ++m)
#pragma unroll
        for (int n = 0; n < 4; ++n)
            acc[m][n] = (f32x4){0.f, 0.f, 0.f, 0.f};

#pragma unroll
    for (int kk = 0; kk < 8; ++kk) {
        bf16x8 af[8];
        int kbyte = kk * 64 + lg * 16;
#pragma unroll
        for (int m = 0; m < 8; ++m) {
            int r = m * 16 + l15;
            af[m] = *(const bf16x8*)(atile + r * 512 + (kbyte ^ ((r & 7) << 4)));
        }
        bf16x8 bfr[4];
#pragma unroll
        for (int n = 0; n < 4; ++n) {
            int cg = wave * 4 + n;
            bfr[n] = *(const bf16x8*)((const char*)w1f + (((cg * 8 + kk) * 64 + lane) << 4));
        }
#pragma unroll
        for (int m = 0; m < 8; ++m)
#pragma unroll
            for (int n = 0; n < 4; ++n)
                acc[m][n] = __builtin_amdgcn_mfma_f32_16x16x32_bf16(af[m], bfr[n], acc[m][n], 0, 0, 0);
    }

    // ---- epilogue: fp32 bias + relu + dot with W2, reduce across lanes/waves ----
    float bb[4], ww[4];
#pragma unroll
    for (int n = 0; n < 4; ++n) {
        int col = wave * 64 + n * 16 + l15;
        bb[n] = b1[col];
        ww[n] = w2p[col];
    }
#pragma unroll
    for (int m = 0; m < 8; ++m) {
        float s[4] = {0.f, 0.f, 0.f, 0.f};
#pragma unroll
        for (int n = 0; n < 4; ++n) {
#pragma unroll
            for (int r = 0; r < 4; ++r) {
                float h = acc[m][n][r] + bb[n];
                h = fmaxf(h, 0.f);
                s[r] = fmaf(h, ww[n], s[r]);
            }
        }
#pragma unroll
        for (int r = 0; r < 4; ++r) {
            float v = s[r];
            v += __shfl_xor(v, 1);
            v += __shfl_xor(v, 2);
            v += __shfl_xor(v, 4);
            v += __shfl_xor(v, 8);
            if (l15 == 0) outp[wave][m * 16 + lg * 4 + r] = v;
        }
    }
    __syncthreads();

    if (tid < BM) {
        long p = base_p + tid;
        if (p < NPAIRS)
            out[p] = outp[0][tid] + outp[1][tid] + outp[2][tid] + outp[3][tid] + b2[0];
    }
}

extern "C" void kernel_launch(void* const* d_in, const int* in_sizes, int n_in,
                              void* d_out, int out_size, void* d_ws, size_t ws_size,
                              hipStream_t stream) {
    const float* x    = (const float*)d_in[0];
    const int*   junc = (const int*)  d_in[1];
    const float* W1   = (const float*)d_in[2];
    const float* b1   = (const float*)d_in[3];
    const float* W2   = (const float*)d_in[4];
    const float* b2   = (const float*)d_in[5];
    float* out = (float*)d_out;
    bf16*  w1f = (bf16*)d_ws;   // 128 KB of packed bf16 W1 fragments

    hipLaunchKernelGGL(pack_w1, dim3(32), dim3(256), 0, stream, W1, w1f);
    hipLaunchKernelGGL(gnn_main, dim3(NBLK), dim3(256), 0, stream,
                       x, junc, w1f, b1, W2, b2, out);
}

// Round 2
// 129.033 us; speedup vs baseline: 1.3500x; 1.3500x over previous
//
#include <hip/hip_runtime.h>
#include <hip/hip_bf16.h>
#include <stdint.h>

#define NPAIRS 500000
#define NNODES 100000
#define DIM    128
#define D2     256
#define BM     128
#define NBLK   ((NPAIRS + BM - 1) / BM)   // 3907

typedef __bf16 bf16;
typedef __bf16 bf16x8 __attribute__((ext_vector_type(8)));
typedef float  f32x4  __attribute__((ext_vector_type(4)));

// ---- prep: x (fp32, 100000x128) -> bf16, contiguous rows of 256B ----
__global__ void convert_x(const float* __restrict__ x, bf16* __restrict__ xb) {
    long t = (long)blockIdx.x * 256 + threadIdx.x;   // 1,600,000 threads exactly
    const float4* src = (const float4*)(x + t * 8);
    float4 a = src[0], b = src[1];
    bf16x8 v;
    v[0] = (bf16)a.x; v[1] = (bf16)a.y; v[2] = (bf16)a.z; v[3] = (bf16)a.w;
    v[4] = (bf16)b.x; v[5] = (bf16)b.y; v[6] = (bf16)b.z; v[7] = (bf16)b.w;
    *(bf16x8*)(xb + t * 8) = v;
}

// ---- prep: W1 (256x256 fp32) -> bf16 MFMA B-fragments in per-lane order ----
// w1f[((cg*8 + kk)*64 + lane)*8 + j] = W1[kk*32 + (lane>>4)*8 + j][cg*16 + (lane&15)]
__global__ void pack_w1(const float* __restrict__ W1, bf16* __restrict__ w1f) {
    int t = blockIdx.x * 256 + threadIdx.x;   // 0..8191
    int lane = t & 63;
    int kkcg = t >> 6;
    int kk = kkcg & 7;
    int cg = kkcg >> 3;
    int l15 = lane & 15, lg = lane >> 4;
    bf16x8 v;
#pragma unroll
    for (int j = 0; j < 8; ++j) {
        int k = kk * 32 + lg * 8 + j;
        int n = cg * 16 + l15;
        v[j] = (bf16)W1[k * D2 + n];
    }
    *(bf16x8*)((char*)w1f + ((long)t << 4)) = v;
}

__device__ __forceinline__ void gld16(void* lds, const void* g) {
    __builtin_amdgcn_global_load_lds(
        (const __attribute__((address_space(1))) uint32_t*)g,
        (__attribute__((address_space(3))) uint32_t*)lds, 16, 0, 0);
}

// 8 waves, BM=128 pairs/block. Wave w owns H cols [w*32, w*32+32).
template<bool PRE>
__launch_bounds__(512, 4)
__global__ void gnn_main(const float* __restrict__ x,
                         const bf16*  __restrict__ xb,
                         const int*   __restrict__ junc,
                         const bf16*  __restrict__ w1f,
                         const float* __restrict__ b1,
                         const float* __restrict__ w2p,
                         const float* __restrict__ b2,
                         float*       __restrict__ out) {
    __shared__ char  atile[BM * 512];   // 64 KB: [128 rows][256 bf16], XOR-swizzled
    __shared__ float outp[8][BM];       // 4 KB per-wave partial row sums

    int tid  = threadIdx.x;
    int wave = tid >> 6, lane = tid & 63;
    long base_p = (long)blockIdx.x * BM;

    if (PRE) {
        // Async gather, linear LDS dest + inverse-swizzled bf16 global source.
        // 8 issues/wave x 1024B (HW: lane i lands at base + i*16).
        const char* gsrc[8];
        int wbase = wave * 8192;
#pragma unroll
        for (int i = 0; i < 8; ++i) {
            int lds_off = wbase + i * 1024 + lane * 16;
            int r    = lds_off >> 9;          // tile row 0..127
            int q    = lds_off & 511;
            int sbir = q ^ ((r & 7) << 4);    // inverse swizzle (involution)
            int side = sbir >> 8;
            long p   = base_p + r;
            int idx  = (p < NPAIRS) ? junc[p * 2 + side] : 0;
            gsrc[i]  = (const char*)xb + ((long)idx << 8) + (sbir & 255);
        }
#pragma unroll
        for (int i = 0; i < 8; ++i)
            gld16(atile + wbase + i * 1024, gsrc[i]);
    } else {
        // Fallback: fp32 gather + in-kernel convert, reg-staged swizzled writes.
#pragma unroll
        for (int it = 0; it < 8; ++it) {
            int task  = it * 512 + tid;       // 0..4095
            int nr    = task >> 4;
            int chunk = task & 15;
            int r     = nr >> 1;
            int side  = nr & 1;
            long p    = base_p + r;
            int idx   = (p < NPAIRS) ? junc[p * 2 + side] : 0;
            const float4* src = (const float4*)(x + (long)idx * DIM + chunk * 8);
            float4 a = src[0], b = src[1];
            bf16x8 v;
            v[0] = (bf16)a.x; v[1] = (bf16)a.y; v[2] = (bf16)a.z; v[3] = (bf16)a.w;
            v[4] = (bf16)b.x; v[5] = (bf16)b.y; v[6] = (bf16)b.z; v[7] = (bf16)b.w;
            int bir = side * 256 + chunk * 16;
            *(bf16x8*)(atile + r * 512 + (bir ^ ((r & 7) << 4))) = v;
        }
    }
    __syncthreads();

    int l15 = lane & 15, lg = lane >> 4;
    f32x4 acc[8][2];
#pragma unroll
    for (int m = 0; m < 8; ++m)
#pragma unroll
        for (int n = 0; n < 2; ++n)
            acc[m][n] = (f32x4){0.f, 0.f, 0.f, 0.f};

#pragma unroll
    for (int kk = 0; kk < 8; ++kk) {
        bf16x8 af[8];
        int kbyte = kk * 64 + lg * 16;
#pragma unroll
        for (int m = 0; m < 8; ++m) {
            int r = m * 16 + l15;
            af[m] = *(const bf16x8*)(atile + r * 512 + (kbyte ^ ((r & 7) << 4)));
        }
        bf16x8 bfr[2];
#pragma unroll
        for (int n = 0; n < 2; ++n) {
            int cg = wave * 2 + n;
            bfr[n] = *(const bf16x8*)((const char*)w1f + (((cg * 8 + kk) * 64 + lane) << 4));
        }
#pragma unroll
        for (int m = 0; m < 8; ++m)
#pragma unroll
            for (int n = 0; n < 2; ++n)
                acc[m][n] = __builtin_amdgcn_mfma_f32_16x16x32_bf16(af[m], bfr[n], acc[m][n], 0, 0, 0);
    }

    // ---- epilogue: fp32 bias + relu + dot(W2), 16-lane reduce, wave partials ----
    float bb[2], ww[2];
#pragma unroll
    for (int n = 0; n < 2; ++n) {
        int col = wave * 32 + n * 16 + l15;
        bb[n] = b1[col];
        ww[n] = w2p[col];
    }
#pragma unroll
    for (int m = 0; m < 8; ++m) {
        float s[4] = {0.f, 0.f, 0.f, 0.f};
#pragma unroll
        for (int n = 0; n < 2; ++n) {
#pragma unroll
            for (int r = 0; r < 4; ++r) {
                float h = acc[m][n][r] + bb[n];
                h = fmaxf(h, 0.f);
                s[r] = fmaf(h, ww[n], s[r]);
            }
        }
#pragma unroll
        for (int r = 0; r < 4; ++r) {
            float v = s[r];
            v += __shfl_xor(v, 1);
            v += __shfl_xor(v, 2);
            v += __shfl_xor(v, 4);
            v += __shfl_xor(v, 8);
            if (l15 == 0) outp[wave][m * 16 + lg * 4 + r] = v;
        }
    }
    __syncthreads();

    if (tid < BM) {
        long p = base_p + tid;
        if (p < NPAIRS) {
            float v = b2[0];
#pragma unroll
            for (int w = 0; w < 8; ++w) v += outp[w][tid];
            out[p] = v;
        }
    }
}

extern "C" void kernel_launch(void* const* d_in, const int* in_sizes, int n_in,
                              void* d_out, int out_size, void* d_ws, size_t ws_size,
                              hipStream_t stream) {
    const float* x    = (const float*)d_in[0];
    const int*   junc = (const int*)  d_in[1];
    const float* W1   = (const float*)d_in[2];
    const float* b1   = (const float*)d_in[3];
    const float* W2   = (const float*)d_in[4];
    const float* b2   = (const float*)d_in[5];
    float* out = (float*)d_out;

    const size_t XB_BYTES = (size_t)NNODES * DIM * 2;   // 25,600,000
    const size_t NEED     = XB_BYTES + 131072;

    if (ws_size >= NEED) {
        bf16* xb  = (bf16*)d_ws;
        bf16* w1f = (bf16*)((char*)d_ws + XB_BYTES);
        hipLaunchKernelGGL(convert_x, dim3(6250), dim3(256), 0, stream, x, xb);
        hipLaunchKernelGGL(pack_w1, dim3(32), dim3(256), 0, stream, W1, w1f);
        hipLaunchKernelGGL((gnn_main<true>), dim3(NBLK), dim3(512), 0, stream,
                           x, xb, junc, w1f, b1, W2, b2, out);
    } else {
        bf16* w1f = (bf16*)d_ws;
        hipLaunchKernelGGL(pack_w1, dim3(32), dim3(256), 0, stream, W1, w1f);
        hipLaunchKernelGGL((gnn_main<false>), dim3(NBLK), dim3(512), 0, stream,
                           x, (const bf16*)nullptr, junc, w1f, b1, W2, b2, out);
    }
}